// Round 9
// baseline (151.986 us; speedup 1.0000x reference)
//
#include <hip/hip_runtime.h>
#include <hip/hip_bf16.h>

#define N_TOK   16384   // B * N_PEP
#define NREC    10
#define EMB     256
#define TWO_EMB 512
#define OUTD    256

typedef __bf16 bf16x8 __attribute__((ext_vector_type(8)));
typedef float  f32x4  __attribute__((ext_vector_type(4)));

static __device__ __forceinline__ unsigned int f2bf_bits(float f) {
    unsigned int u = __builtin_bit_cast(unsigned int, f);
    u = (u + 0x7fffu + ((u >> 16) & 1u)) >> 16;   // RNE bf16
    return u & 0xffffu;
}
static __device__ __forceinline__ unsigned int pack2(float a, float b) {
    return f2bf_bits(a) | (f2bf_bits(b) << 16);
}
static __device__ __forceinline__ float bflo(unsigned int u) {
    return __builtin_bit_cast(float, u << 16);
}
static __device__ __forceinline__ float bfhi(unsigned int u) {
    return __builtin_bit_cast(float, u & 0xffff0000u);
}
static __device__ __forceinline__ bf16x8 pack8(float4 f0, float4 f1) {
    uint4 t = { pack2(f0.x, f0.y), pack2(f0.z, f0.w), pack2(f1.x, f1.y), pack2(f1.z, f1.w) };
    return __builtin_bit_cast(bf16x8, t);
}

// 64-lane sum: 4 DPP row_ror adds (16-lane ring, VALU latency) + 2 shuffles.
static __device__ __forceinline__ float wave_sum(float p) {
    p += __builtin_bit_cast(float, __builtin_amdgcn_update_dpp(
             0, __builtin_bit_cast(int, p), 0x121, 0xf, 0xf, true));
    p += __builtin_bit_cast(float, __builtin_amdgcn_update_dpp(
             0, __builtin_bit_cast(int, p), 0x122, 0xf, 0xf, true));
    p += __builtin_bit_cast(float, __builtin_amdgcn_update_dpp(
             0, __builtin_bit_cast(int, p), 0x124, 0xf, 0xf, true));
    p += __builtin_bit_cast(float, __builtin_amdgcn_update_dpp(
             0, __builtin_bit_cast(int, p), 0x128, 0xf, 0xf, true));
    p += __shfl_xor(p, 16);
    p += __shfl_xor(p, 32);
    return p;
}

// ---------------- weight fragment prep (bf16, MFMA B-fragment order) ----------
__global__ void prep_wfrag(const float* __restrict__ Wp,
                           const float* __restrict__ Wr,
                           const float* __restrict__ Wv,
                           short* __restrict__ wp_frag,
                           short* __restrict__ wr_frag,
                           short* __restrict__ wv_frag) {
    int idx = blockIdx.x * blockDim.x + threadIdx.x;   // grid covers 131072
    if (idx < 16 * 8 * 64 * 8) {
        int j = idx & 7, lane = (idx >> 3) & 63, kt = (idx >> 9) & 7, nt = idx >> 12;
        int n = nt * 16 + (lane & 15), k = kt * 32 + ((lane >> 4) << 3) + j;
        wp_frag[idx] = (short)f2bf_bits(Wp[n * EMB + k]);
    }
    if (idx < 32 * 8 * 64 * 8) {
        int j = idx & 7, lane = (idx >> 3) & 63, kt = (idx >> 9) & 7, nt = idx >> 12;
        int n = nt * 16 + (lane & 15), k = kt * 32 + ((lane >> 4) << 3) + j;
        wr_frag[idx] = (short)f2bf_bits(Wr[k * TWO_EMB + n]);
    }
    if (idx < 16 * 16 * 64 * 8) {
        int j = idx & 7, lane = (idx >> 3) & 63, kt = (idx >> 9) & 15, nt = idx >> 13;
        int n = nt * 16 + (lane & 15), k = kt * 32 + ((lane >> 4) << 3) + j;
        wv_frag[idx] = (short)f2bf_bits(Wv[n * TWO_EMB + k]);
    }
}

// B-fragment loaders (frag path or direct-from-f32 fallback)
template<int USE_FRAG>
static __device__ __forceinline__ bf16x8 load_b_rm(const short* __restrict__ frag,
                                                   const float* __restrict__ W,
                                                   int n, int k, int ld) {
    if constexpr (USE_FRAG) {
        return *reinterpret_cast<const bf16x8*>(frag);
    } else {
        const float* s = W + (long)n * ld + k;
        return pack8(*reinterpret_cast<const float4*>(s),
                     *reinterpret_cast<const float4*>(s + 4));
    }
}
template<int USE_FRAG>
static __device__ __forceinline__ bf16x8 load_b_tr(const short* __restrict__ frag,
                                                   const float* __restrict__ W,
                                                   int n, int k, int ld) {
    if constexpr (USE_FRAG) {
        return *reinterpret_cast<const bf16x8*>(frag);
    } else {
        unsigned int p[4];
        #pragma unroll
        for (int jj = 0; jj < 4; ++jj)
            p[jj] = pack2(W[(long)(k + 2 * jj) * ld + n], W[(long)(k + 2 * jj + 1) * ld + n]);
        uint4 t = { p[0], p[1], p[2], p[3] };
        return __builtin_bit_cast(bf16x8, t);
    }
}

// ======================= Kernel A: q + qr projections =========================
// q = Wp@pep + bp  -> qws (bf16 [tok][256]);  qr = Wr^T q -> qrws (bf16 [tok][512])
// qrws lives in d_out (16 MB bf16 == out_size f32 bytes).
template<int USE_FRAG>
__launch_bounds__(256, 4)
__global__ void ga_qr(const float* __restrict__ pep,
                      const float* __restrict__ Wp_w,
                      const float* __restrict__ Wp_b,
                      const float* __restrict__ Wr_w,
                      const short* __restrict__ wp_frag,
                      const short* __restrict__ wr_frag,
                      unsigned short* __restrict__ qws,
                      unsigned short* __restrict__ qrws) {
    __shared__ __align__(16) unsigned char qbf[16 * 512];   // 8 KB, swizzled bf16 q tile

    const int tid  = threadIdx.x;
    const int lane = tid & 63;
    const int wave = tid >> 6;            // 0..3
    const int tok0 = blockIdx.x * 16;

    // ---- 1a: q (M=16,K=256,N=256; 4 nt/wave in 2 passes); pep read direct ----
    #pragma unroll
    for (int pass = 0; pass < 2; ++pass) {
        f32x4 qacc[2] = {};
        #pragma unroll
        for (int kt = 0; kt < 8; ++kt) {
            int kk = kt * 32 + ((lane >> 4) << 3);
            int row = lane & 15;
            const float* s = pep + (long)(tok0 + row) * EMB + kk;
            bf16x8 a = pack8(*reinterpret_cast<const float4*>(s),
                             *reinterpret_cast<const float4*>(s + 4));
            #pragma unroll
            for (int ntl = 0; ntl < 2; ++ntl) {
                int nt = wave * 4 + pass * 2 + ntl;
                bf16x8 b = load_b_rm<USE_FRAG>(wp_frag + ((nt * 8 + kt) * 64 + lane) * 8,
                                               Wp_w, nt * 16 + (lane & 15), kk, EMB);
                qacc[ntl] = __builtin_amdgcn_mfma_f32_16x16x32_bf16(a, b, qacc[ntl], 0, 0, 0);
            }
        }
        #pragma unroll
        for (int ntl = 0; ntl < 2; ++ntl) {
            int n = (wave * 4 + pass * 2 + ntl) * 16 + (lane & 15);
            float bias = Wp_b[n];
            #pragma unroll
            for (int i = 0; i < 4; ++i) {
                int row = ((lane >> 4) << 2) + i;
                unsigned short u = (unsigned short)f2bf_bits(qacc[ntl][i] + bias);
                *reinterpret_cast<unsigned short*>(qbf + 512 * row + ((n * 2) ^ ((row & 7) << 4))) = u;
                qws[(long)(tok0 + row) * OUTD + n] = u;
            }
        }
    }
    __syncthreads();

    // ---- 1b: qr (M=16,K=256,N=512; 8 nt/wave in 4 passes) -> qrws bf16 ----
    #pragma unroll
    for (int pass = 0; pass < 4; ++pass) {
        f32x4 racc[2] = {};
        #pragma unroll
        for (int kt = 0; kt < 8; ++kt) {
            int kk = kt * 32 + ((lane >> 4) << 3);
            int row = lane & 15;
            bf16x8 a = *reinterpret_cast<const bf16x8*>(qbf + 512 * row + ((kk * 2) ^ ((row & 7) << 4)));
            #pragma unroll
            for (int ntl = 0; ntl < 2; ++ntl) {
                int nt = wave * 8 + pass * 2 + ntl;
                bf16x8 b = load_b_tr<USE_FRAG>(wr_frag + ((nt * 8 + kt) * 64 + lane) * 8,
                                               Wr_w, nt * 16 + (lane & 15), kk, TWO_EMB);
                racc[ntl] = __builtin_amdgcn_mfma_f32_16x16x32_bf16(a, b, racc[ntl], 0, 0, 0);
            }
        }
        #pragma unroll
        for (int ntl = 0; ntl < 2; ++ntl) {
            int n = (wave * 8 + pass * 2 + ntl) * 16 + (lane & 15);
            #pragma unroll
            for (int i = 0; i < 4; ++i) {
                int row = ((lane >> 4) << 2) + i;
                qrws[(long)(tok0 + row) * TWO_EMB + n] = (unsigned short)f2bf_bits(racc[ntl][i]);
            }
        }
    }
}

// ======================= Kernel B: streaming softmax+xbar =====================
// One wave per token; no LDS, no barriers, no MFMA -> 8 waves/SIMD.
// Reads qr[t] (bf16) from qr_xbar, streams 10 rows of [rec|edge], writes xbar
// bf16 IN PLACE over qr[t] (each wave reads its 16B before its final write).
__launch_bounds__(256, 8)
__global__ void ga_stream(const float* __restrict__ rec,
                          const float* __restrict__ edge,
                          unsigned short* qr_xbar) {
    const int lane = threadIdx.x & 63;
    const int wave = threadIdx.x >> 6;
    const int t = blockIdx.x * 4 + wave;

    const float* srcA = (lane < 32) ? rec : edge;
    const int dloc = (lane * 8) & 255;
    const float* bp = srcA + (long)t * NREC * EMB + dloc;

    uint4 qw = *reinterpret_cast<const uint4*>(qr_xbar + (long)t * TWO_EMB + lane * 8);
    const float qa0 = bflo(qw.x), qa1 = bfhi(qw.x), qa2 = bflo(qw.y), qa3 = bfhi(qw.y);
    const float qa4 = bflo(qw.z), qa5 = bfhi(qw.z), qa6 = bflo(qw.w), qa7 = bfhi(qw.w);
    const float Cc = 0.0625f * 1.4426950408889634f;   // 1/sqrt(256) * log2(e)

    float4 s0l = *reinterpret_cast<const float4*>(bp + 0 * EMB);
    float4 s0h = *reinterpret_cast<const float4*>(bp + 0 * EMB + 4);
    float4 s1l = *reinterpret_cast<const float4*>(bp + 1 * EMB);
    float4 s1h = *reinterpret_cast<const float4*>(bp + 1 * EMB + 4);
    float4 s2l = *reinterpret_cast<const float4*>(bp + 2 * EMB);
    float4 s2h = *reinterpret_cast<const float4*>(bp + 2 * EMB + 4);
    float4 s3l = *reinterpret_cast<const float4*>(bp + 3 * EMB);
    float4 s3h = *reinterpret_cast<const float4*>(bp + 3 * EMB + 4);

    float s = 0.f;
    float4 xb0 = make_float4(0.f, 0.f, 0.f, 0.f), xb1 = xb0;

    #define LD(r, sl, sh) { sl = *reinterpret_cast<const float4*>(bp + (r) * EMB); \
                            sh = *reinterpret_cast<const float4*>(bp + (r) * EMB + 4); }
    #define PROC(sl, sh) { \
        float p = qa0*(sl).x + qa1*(sl).y + qa2*(sl).z + qa3*(sl).w \
                + qa4*(sh).x + qa5*(sh).y + qa6*(sh).z + qa7*(sh).w; \
        p = wave_sum(p); \
        float e = exp2f(p * Cc);                     /* no-max: |logit| <~ 2 */ \
        s += e; \
        xb0.x += e*(sl).x; xb0.y += e*(sl).y; xb0.z += e*(sl).z; xb0.w += e*(sl).w; \
        xb1.x += e*(sh).x; xb1.y += e*(sh).y; xb1.z += e*(sh).z; xb1.w += e*(sh).w; }

    PROC(s0l, s0h); LD(4, s0l, s0h);
    PROC(s1l, s1h); LD(5, s1l, s1h);
    PROC(s2l, s2h); LD(6, s2l, s2h);
    PROC(s3l, s3h); LD(7, s3l, s3h);
    PROC(s0l, s0h); LD(8, s0l, s0h);
    PROC(s1l, s1h); LD(9, s1l, s1h);
    PROC(s2l, s2h);
    PROC(s3l, s3h);
    PROC(s0l, s0h);
    PROC(s1l, s1h);
    #undef LD
    #undef PROC

    const float inv = 1.f / s;
    uint4 wv4 = { pack2(xb0.x * inv, xb0.y * inv), pack2(xb0.z * inv, xb0.w * inv),
                  pack2(xb1.x * inv, xb1.y * inv), pack2(xb1.z * inv, xb1.w * inv) };
    *reinterpret_cast<uint4*>(qr_xbar + (long)t * TWO_EMB + lane * 8) = wv4;
}

// ======================= Kernel C: out = q + Wv@xbar + bv =====================
// xbar read as MFMA A-frags DIRECT from d_out (bf16); after all K reads a
// barrier, then d_out is overwritten with f32 output (same byte range).
template<int USE_FRAG>
__launch_bounds__(256, 4)
__global__ void ga_out(void* dout,
                       const unsigned short* __restrict__ qws,
                       const float* __restrict__ Wv_w,
                       const float* __restrict__ Wv_b,
                       const short* __restrict__ wv_frag) {
    const unsigned short* xbar = (const unsigned short*)dout;   // aliases out!
    float* out = (float*)dout;

    const int tid  = threadIdx.x;
    const int lane = tid & 63;
    const int wave = tid >> 6;
    const int tok0 = blockIdx.x * 16;

    f32x4 oacc[4] = {};
    #pragma unroll
    for (int kt = 0; kt < 16; ++kt) {
        int kk = kt * 32 + ((lane >> 4) << 3);
        int row = lane & 15;
        bf16x8 a = *reinterpret_cast<const bf16x8*>(xbar + (long)(tok0 + row) * TWO_EMB + kk);
        #pragma unroll
        for (int ntl = 0; ntl < 4; ++ntl) {
            int nt = wave * 4 + ntl;
            bf16x8 b = load_b_rm<USE_FRAG>(wv_frag + ((nt * 16 + kt) * 64 + lane) * 8,
                                           Wv_w, nt * 16 + (lane & 15), kk, TWO_EMB);
            oacc[ntl] = __builtin_amdgcn_mfma_f32_16x16x32_bf16(a, b, oacc[ntl], 0, 0, 0);
        }
    }
    __syncthreads();   // ALL xbar reads complete before ANY out write (same bytes)

    #pragma unroll
    for (int ntl = 0; ntl < 4; ++ntl) {
        int n = (wave * 4 + ntl) * 16 + (lane & 15);
        float bv = Wv_b[n];
        #pragma unroll
        for (int i = 0; i < 4; ++i) {
            int row = ((lane >> 4) << 2) + i;
            float qv = bflo((unsigned int)qws[(long)(tok0 + row) * OUTD + n]);
            out[(long)(tok0 + row) * OUTD + n] = qv + oacc[ntl][i] + bv;
        }
    }
}

// ======================= Fallback: fused (R6 structure, no ws) ================
static __device__ __forceinline__ void stream_token_f(
    const float* __restrict__ bp, const unsigned char* __restrict__ qrb,
    unsigned char* __restrict__ xz, int t, int lane,
    float4 s0l, float4 s0h, float4 s1l, float4 s1h,
    float4 s2l, float4 s2h, float4 s3l, float4 s3h)
{
    uint4 qw = *reinterpret_cast<const uint4*>(qrb + t * 1024 + lane * 16);
    const float qa0 = bflo(qw.x), qa1 = bfhi(qw.x), qa2 = bflo(qw.y), qa3 = bfhi(qw.y);
    const float qa4 = bflo(qw.z), qa5 = bfhi(qw.z), qa6 = bflo(qw.w), qa7 = bfhi(qw.w);
    const float Cc = 0.0625f * 1.4426950408889634f;
    float s = 0.f;
    float4 xb0 = make_float4(0.f, 0.f, 0.f, 0.f), xb1 = xb0;
    #define LD(r, sl, sh) { sl = *reinterpret_cast<const float4*>(bp + (r) * EMB); \
                            sh = *reinterpret_cast<const float4*>(bp + (r) * EMB + 4); }
    #define PROC(sl, sh) { \
        float p = qa0*(sl).x + qa1*(sl).y + qa2*(sl).z + qa3*(sl).w \
                + qa4*(sh).x + qa5*(sh).y + qa6*(sh).z + qa7*(sh).w; \
        p = wave_sum(p); \
        float e = exp2f(p * Cc); \
        s += e; \
        xb0.x += e*(sl).x; xb0.y += e*(sl).y; xb0.z += e*(sl).z; xb0.w += e*(sl).w; \
        xb1.x += e*(sh).x; xb1.y += e*(sh).y; xb1.z += e*(sh).z; xb1.w += e*(sh).w; }
    PROC(s0l, s0h); LD(4, s0l, s0h);
    PROC(s1l, s1h); LD(5, s1l, s1h);
    PROC(s2l, s2h); LD(6, s2l, s2h);
    PROC(s3l, s3h); LD(7, s3l, s3h);
    PROC(s0l, s0h); LD(8, s0l, s0h);
    PROC(s1l, s1h); LD(9, s1l, s1h);
    PROC(s2l, s2h);
    PROC(s3l, s3h);
    PROC(s0l, s0h);
    PROC(s1l, s1h);
    #undef LD
    #undef PROC
    const float inv = 1.f / s;
    uint4 wv4 = { pack2(xb0.x * inv, xb0.y * inv), pack2(xb0.z * inv, xb0.w * inv),
                  pack2(xb1.x * inv, xb1.y * inv), pack2(xb1.z * inv, xb1.w * inv) };
    *reinterpret_cast<uint4*>(xz + 1024 * t + ((lane * 16) ^ ((t & 7) << 4))) = wv4;
}

__launch_bounds__(512, 4)
__global__ void ga_fallback(const float* __restrict__ rec,
                            const float* __restrict__ pep,
                            const float* __restrict__ edge,
                            const float* __restrict__ Wp_w,
                            const float* __restrict__ Wp_b,
                            const float* __restrict__ Wr_w,
                            const float* __restrict__ Wv_w,
                            const float* __restrict__ Wv_b,
                            float* __restrict__ out) {
    __shared__ __align__(16) unsigned char xz[16 * 1024];
    __shared__ __align__(16) unsigned char qbf[16 * 512];
    __shared__ __align__(16) unsigned char qrb[16 * 1024];
    const int tid  = threadIdx.x;
    const int lane = tid & 63;
    const int wave = tid >> 6;
    const int tok0 = blockIdx.x * 16;

    #pragma unroll
    for (int it = 0; it < 2; ++it) {
        int idx = tid + it * 512;
        int row = idx >> 6, d4 = (idx & 63) << 2;
        float4 f = *reinterpret_cast<const float4*>(pep + (long)(tok0 + row) * EMB + d4);
        uint2 w = { pack2(f.x, f.y), pack2(f.z, f.w) };
        *reinterpret_cast<uint2*>(xz + 512 * row + ((d4 * 2) ^ ((row & 7) << 4))) = w;
    }
    __syncthreads();

    {
        f32x4 qacc[2] = {};
        #pragma unroll
        for (int kt = 0; kt < 8; ++kt) {
            int kk = kt * 32 + ((lane >> 4) << 3);
            int row = lane & 15;
            bf16x8 a = *reinterpret_cast<const bf16x8*>(xz + 512 * row + ((kk * 2) ^ ((row & 7) << 4)));
            #pragma unroll
            for (int ntl = 0; ntl < 2; ++ntl) {
                int nt = wave * 2 + ntl;
                bf16x8 b = load_b_rm<0>(nullptr, Wp_w, nt * 16 + (lane & 15), kk, EMB);
                qacc[ntl] = __builtin_amdgcn_mfma_f32_16x16x32_bf16(a, b, qacc[ntl], 0, 0, 0);
            }
        }
        #pragma unroll
        for (int ntl = 0; ntl < 2; ++ntl) {
            int n = (wave * 2 + ntl) * 16 + (lane & 15);
            float bias = Wp_b[n];
            #pragma unroll
            for (int i = 0; i < 4; ++i) {
                int row = ((lane >> 4) << 2) + i;
                *reinterpret_cast<unsigned short*>(qbf + 512 * row + ((n * 2) ^ ((row & 7) << 4)))
                    = (unsigned short)f2bf_bits(qacc[ntl][i] + bias);
            }
        }
    }

    const float* srcA = (lane < 32) ? rec : edge;
    const int dloc = (lane * 8) & 255;
    const float* baseA = srcA + (long)(tok0 + wave * 2) * NREC * EMB + dloc;
    const float* baseB = baseA + (long)NREC * EMB;
    float4 a0l = *reinterpret_cast<const float4*>(baseA + 0 * EMB);
    float4 a0h = *reinterpret_cast<const float4*>(baseA + 0 * EMB + 4);
    float4 a1l = *reinterpret_cast<const float4*>(baseA + 1 * EMB);
    float4 a1h = *reinterpret_cast<const float4*>(baseA + 1 * EMB + 4);
    float4 a2l = *reinterpret_cast<const float4*>(baseA + 2 * EMB);
    float4 a2h = *reinterpret_cast<const float4*>(baseA + 2 * EMB + 4);
    float4 a3l = *reinterpret_cast<const float4*>(baseA + 3 * EMB);
    float4 a3h = *reinterpret_cast<const float4*>(baseA + 3 * EMB + 4);
    __syncthreads();

    #pragma unroll
    for (int pass = 0; pass < 1; ++pass) {
        f32x4 racc[4] = {};
        #pragma unroll
        for (int kt = 0; kt < 8; ++kt) {
            int kk = kt * 32 + ((lane >> 4) << 3);
            int row = lane & 15;
            bf16x8 a = *reinterpret_cast<const bf16x8*>(qbf + 512 * row + ((kk * 2) ^ ((row & 7) << 4)));
            #pragma unroll
            for (int ntl = 0; ntl < 4; ++ntl) {
                int nt = wave * 4 + ntl;
                bf16x8 b = load_b_tr<0>(nullptr, Wr_w, nt * 16 + (lane & 15), kk, TWO_EMB);
                racc[ntl] = __builtin_amdgcn_mfma_f32_16x16x32_bf16(a, b, racc[ntl], 0, 0, 0);
            }
        }
        #pragma unroll
        for (int ntl = 0; ntl < 4; ++ntl) {
            int n = (wave * 4 + ntl) * 16 + (lane & 15);
            #pragma unroll
            for (int i = 0; i < 4; ++i) {
                int row = ((lane >> 4) << 2) + i;
                *reinterpret_cast<unsigned short*>(qrb + row * 1024 + n * 2)
                    = (unsigned short)f2bf_bits(racc[ntl][i]);
            }
        }
    }
    __syncthreads();

    stream_token_f(baseA, qrb, xz, wave * 2, lane, a0l, a0h, a1l, a1h, a2l, a2h, a3l, a3h);
    {
        float4 b0l = *reinterpret_cast<const float4*>(baseB + 0 * EMB);
        float4 b0h = *reinterpret_cast<const float4*>(baseB + 0 * EMB + 4);
        float4 b1l = *reinterpret_cast<const float4*>(baseB + 1 * EMB);
        float4 b1h = *reinterpret_cast<const float4*>(baseB + 1 * EMB + 4);
        float4 b2l = *reinterpret_cast<const float4*>(baseB + 2 * EMB);
        float4 b2h = *reinterpret_cast<const float4*>(baseB + 2 * EMB + 4);
        float4 b3l = *reinterpret_cast<const float4*>(baseB + 3 * EMB);
        float4 b3h = *reinterpret_cast<const float4*>(baseB + 3 * EMB + 4);
        stream_token_f(baseB, qrb, xz, wave * 2 + 1, lane, b0l, b0h, b1l, b1h, b2l, b2h, b3l, b3h);
    }
    __syncthreads();

    #pragma unroll
    for (int pass = 0; pass < 2; ++pass) {
        f32x4 oacc[2] = {};
        #pragma unroll
        for (int kt = 0; kt < 16; ++kt) {
            int kk = kt * 32 + ((lane >> 4) << 3);
            int row = lane & 15;
            bf16x8 a = *reinterpret_cast<const bf16x8*>(xz + 1024 * row + ((kk * 2) ^ ((row & 7) << 4)));
            #pragma unroll
            for (int ntl = 0; ntl < 2; ++ntl) {
                int nt = wave * 2 + pass + ntl * 2;   // cover 4 n-tiles over 2 passes
                bf16x8 b = load_b_rm<0>(nullptr, Wv_w, nt * 16 + (lane & 15), kk, TWO_EMB);
                oacc[ntl] = __builtin_amdgcn_mfma_f32_16x16x32_bf16(a, b, oacc[ntl], 0, 0, 0);
            }
        }
        #pragma unroll
        for (int ntl = 0; ntl < 2; ++ntl) {
            int n = (wave * 2 + pass + ntl * 2) * 16 + (lane & 15);
            float bv = Wv_b[n];
            #pragma unroll
            for (int i = 0; i < 4; ++i) {
                int row = ((lane >> 4) << 2) + i;
                unsigned short qu = *reinterpret_cast<const unsigned short*>(
                    qbf + 512 * row + ((n * 2) ^ ((row & 7) << 4)));
                out[(long)(tok0 + row) * OUTD + n] = bflo((unsigned int)qu) + oacc[ntl][i] + bv;
            }
        }
    }
}

extern "C" void kernel_launch(void* const* d_in, const int* in_sizes, int n_in,
                              void* d_out, int out_size, void* d_ws, size_t ws_size,
                              hipStream_t stream) {
    const float* rec  = (const float*)d_in[0];
    const float* pep  = (const float*)d_in[1];
    const float* edge = (const float*)d_in[2];
    const float* Wp_w = (const float*)d_in[3];
    const float* Wp_b = (const float*)d_in[4];
    const float* Wr_w = (const float*)d_in[5];
    // d_in[6] = Wr_b : irrelevant (softmax shift invariance)
    const float* Wv_w = (const float*)d_in[7];
    const float* Wv_b = (const float*)d_in[8];

    const size_t wp_elems = 16 * 8 * 64 * 8;    // 65536
    const size_t wr_elems = 32 * 8 * 64 * 8;    // 131072
    const size_t wv_elems = 16 * 16 * 64 * 8;   // 131072
    const size_t frag_bytes = (wp_elems + wr_elems + wv_elems) * sizeof(short);  // 655360
    const size_t q_bytes = (size_t)N_TOK * OUTD * sizeof(unsigned short);        // 8 MB
    const size_t need = frag_bytes + q_bytes;

    short* wp_frag = (short*)d_ws;
    short* wr_frag = wp_frag + wp_elems;
    short* wv_frag = wr_frag + wr_elems;
    unsigned short* qws = (unsigned short*)((char*)d_ws + frag_bytes);

    if (ws_size >= need) {
        prep_wfrag<<<512, 256, 0, stream>>>(Wp_w, Wr_w, Wv_w, wp_frag, wr_frag, wv_frag);
        ga_qr<1><<<N_TOK / 16, 256, 0, stream>>>(pep, Wp_w, Wp_b, Wr_w, wp_frag, wr_frag,
                                                 qws, (unsigned short*)d_out);
        ga_stream<<<N_TOK / 4, 256, 0, stream>>>(rec, edge, (unsigned short*)d_out);
        ga_out<1><<<N_TOK / 16, 256, 0, stream>>>(d_out, qws, Wv_w, Wv_b, wv_frag);
    } else {
        ga_fallback<<<N_TOK / 16, 512, 0, stream>>>(rec, pep, edge, Wp_w, Wp_b, Wr_w,
                                                    Wv_w, Wv_b, (float*)d_out);
    }
}

// Round 10
// 150.579 us; speedup vs baseline: 1.0093x; 1.0093x over previous
//
#include <hip/hip_runtime.h>
#include <hip/hip_bf16.h>

#define N_TOK   16384   // B * N_PEP
#define NREC    10
#define EMB     256
#define TWO_EMB 512
#define OUTD    256
#define T_BLK   16      // tokens per block
#define THREADS 512     // 8 waves; wave w streams tokens 2w, 2w+1 interleaved

typedef __bf16 bf16x8 __attribute__((ext_vector_type(8)));
typedef float  f32x4  __attribute__((ext_vector_type(4)));

static __device__ __forceinline__ unsigned int f2bf_bits(float f) {
    unsigned int u = __builtin_bit_cast(unsigned int, f);
    u = (u + 0x7fffu + ((u >> 16) & 1u)) >> 16;   // RNE bf16
    return u & 0xffffu;
}
static __device__ __forceinline__ unsigned int pack2(float a, float b) {
    return f2bf_bits(a) | (f2bf_bits(b) << 16);
}
static __device__ __forceinline__ float bflo(unsigned int u) {
    return __builtin_bit_cast(float, u << 16);
}
static __device__ __forceinline__ float bfhi(unsigned int u) {
    return __builtin_bit_cast(float, u & 0xffff0000u);
}

// Non-CSE-able bf16 unpack: keeps the packed qr in 4 regs/token instead of 16
// unpacked floats live across the whole streaming loop (asm volatile defeats CSE).
static __device__ __forceinline__ float vlo(unsigned int u) {
    float f;
    asm volatile("v_lshlrev_b32 %0, 16, %1" : "=v"(f) : "v"(u));
    return f;
}
static __device__ __forceinline__ float vhi(unsigned int u) {
    float f;
    asm volatile("v_and_b32 %0, 0xffff0000, %1" : "=v"(f) : "v"(u));
    return f;
}

// 64-lane sum: 4 DPP row_ror adds (16-lane ring, VALU latency) + 2 shuffles.
static __device__ __forceinline__ float wave_sum(float p) {
    p += __builtin_bit_cast(float, __builtin_amdgcn_update_dpp(
             0, __builtin_bit_cast(int, p), 0x121, 0xf, 0xf, true));
    p += __builtin_bit_cast(float, __builtin_amdgcn_update_dpp(
             0, __builtin_bit_cast(int, p), 0x122, 0xf, 0xf, true));
    p += __builtin_bit_cast(float, __builtin_amdgcn_update_dpp(
             0, __builtin_bit_cast(int, p), 0x124, 0xf, 0xf, true));
    p += __builtin_bit_cast(float, __builtin_amdgcn_update_dpp(
             0, __builtin_bit_cast(int, p), 0x128, 0xf, 0xf, true));
    p += __shfl_xor(p, 16);
    p += __shfl_xor(p, 32);
    return p;
}

// ---------------- weight fragment prep (bf16, MFMA B-fragment order) ----------
__global__ void prep_wfrag(const float* __restrict__ Wp,
                           const float* __restrict__ Wr,
                           const float* __restrict__ Wv,
                           short* __restrict__ wp_frag,
                           short* __restrict__ wr_frag,
                           short* __restrict__ wv_frag) {
    int idx = blockIdx.x * blockDim.x + threadIdx.x;   // grid covers 131072
    if (idx < 16 * 8 * 64 * 8) {
        int j = idx & 7, lane = (idx >> 3) & 63, kt = (idx >> 9) & 7, nt = idx >> 12;
        int n = nt * 16 + (lane & 15), k = kt * 32 + ((lane >> 4) << 3) + j;
        wp_frag[idx] = (short)f2bf_bits(Wp[n * EMB + k]);
    }
    if (idx < 32 * 8 * 64 * 8) {
        int j = idx & 7, lane = (idx >> 3) & 63, kt = (idx >> 9) & 7, nt = idx >> 12;
        int n = nt * 16 + (lane & 15), k = kt * 32 + ((lane >> 4) << 3) + j;
        wr_frag[idx] = (short)f2bf_bits(Wr[k * TWO_EMB + n]);
    }
    if (idx < 16 * 16 * 64 * 8) {
        int j = idx & 7, lane = (idx >> 3) & 63, kt = (idx >> 9) & 15, nt = idx >> 13;
        int n = nt * 16 + (lane & 15), k = kt * 32 + ((lane >> 4) << 3) + j;
        wv_frag[idx] = (short)f2bf_bits(Wv[n * TWO_EMB + k]);
    }
}

// B-fragment loaders (frag path or direct-from-f32 fallback)
template<int USE_FRAG>
static __device__ __forceinline__ bf16x8 load_b_rm(const short* __restrict__ frag,
                                                   const float* __restrict__ W,
                                                   int n, int k, int ld) {
    if constexpr (USE_FRAG) {
        return *reinterpret_cast<const bf16x8*>(frag);
    } else {
        const float* s = W + (long)n * ld + k;
        float4 f0 = *reinterpret_cast<const float4*>(s);
        float4 f1 = *reinterpret_cast<const float4*>(s + 4);
        uint4 t = { pack2(f0.x, f0.y), pack2(f0.z, f0.w), pack2(f1.x, f1.y), pack2(f1.z, f1.w) };
        return __builtin_bit_cast(bf16x8, t);
    }
}
template<int USE_FRAG>
static __device__ __forceinline__ bf16x8 load_b_tr(const short* __restrict__ frag,
                                                   const float* __restrict__ W,
                                                   int n, int k, int ld) {
    if constexpr (USE_FRAG) {
        return *reinterpret_cast<const bf16x8*>(frag);
    } else {
        unsigned int p[4];
        #pragma unroll
        for (int jj = 0; jj < 4; ++jj)
            p[jj] = pack2(W[(long)(k + 2 * jj) * ld + n], W[(long)(k + 2 * jj + 1) * ld + n]);
        uint4 t = { p[0], p[1], p[2], p[3] };
        return __builtin_bit_cast(bf16x8, t);
    }
}

// ---------------- fused kernel (commuted-projection formulation) --------------
// per token t:  q  = Wp@pep + bp                      (MFMA; kept in qbf as bf16)
//               qr = Wr^T q                           (MFMA; Wr_b drops: softmax shift-inv)
//               e_r = exp((qr . x_r)/16)              (streamed f32, 2 tokens interleaved)
//               xbar = (sum e_r x_r) / (sum e_r)
//               out = q + Wv@xbar + bv                (MFMA; sum(attn)=1 folds bias)
template<int USE_FRAG>
__launch_bounds__(THREADS, 4)
__global__ void ga8_fused(const float* __restrict__ rec,
                          const float* __restrict__ pep,
                          const float* __restrict__ edge,
                          const float* __restrict__ Wp_w,
                          const float* __restrict__ Wp_b,
                          const float* __restrict__ Wr_w,
                          const float* __restrict__ Wv_w,
                          const float* __restrict__ Wv_b,
                          const short* __restrict__ wp_frag,
                          const short* __restrict__ wr_frag,
                          const short* __restrict__ wv_frag,
                          float* __restrict__ out) {
    // xz: pep bf16 A-tile (512B rows) in 1a, then xbar bf16 A-tile (1024B rows) in ph3
    __shared__ __align__(16) unsigned char xz[T_BLK * 1024];       // 16 KB
    __shared__ __align__(16) unsigned char qbf[T_BLK * 512];       // 8 KB (q bf16 A-tile)
    __shared__ __align__(16) unsigned char qrb[T_BLK * 1024];      // 16 KB (qr bf16 [t][512])

    const int tid  = threadIdx.x;
    const int lane = tid & 63;
    const int wave = tid >> 6;
    const int tok0 = blockIdx.x * T_BLK;

    // ---- stage pep tile as bf16 (swizzled) ----
    #pragma unroll
    for (int it = 0; it < 2; ++it) {
        int idx = tid + it * THREADS;          // 16 rows x 64 float4
        int row = idx >> 6, d4 = (idx & 63) << 2;
        float4 f = *reinterpret_cast<const float4*>(pep + (long)(tok0 + row) * EMB + d4);
        uint2 w = { pack2(f.x, f.y), pack2(f.z, f.w) };
        *reinterpret_cast<uint2*>(xz + 512 * row + ((d4 * 2) ^ ((row & 7) << 4))) = w;
    }
    __syncthreads();                            // B1: pep tile ready

    // ---- 1a: q = pep @ Wp^T + bp  (M=16,K=256,N=256; 2 n-tiles/wave) ----
    {
        f32x4 qacc[2] = {};
        #pragma unroll
        for (int kt = 0; kt < 8; ++kt) {
            int kk = kt * 32 + ((lane >> 4) << 3);
            int row = lane & 15;
            bf16x8 a = *reinterpret_cast<const bf16x8*>(xz + 512 * row + ((kk * 2) ^ ((row & 7) << 4)));
            #pragma unroll
            for (int ntl = 0; ntl < 2; ++ntl) {
                int nt = wave * 2 + ntl;
                bf16x8 b = load_b_rm<USE_FRAG>(wp_frag + ((nt * 8 + kt) * 64 + lane) * 8,
                                               Wp_w, nt * 16 + (lane & 15), kk, EMB);
                qacc[ntl] = __builtin_amdgcn_mfma_f32_16x16x32_bf16(a, b, qacc[ntl], 0, 0, 0);
            }
        }
        #pragma unroll
        for (int ntl = 0; ntl < 2; ++ntl) {
            int n = (wave * 2 + ntl) * 16 + (lane & 15);
            float bias = Wp_b[n];
            #pragma unroll
            for (int i = 0; i < 4; ++i) {
                int row = ((lane >> 4) << 2) + i;
                *reinterpret_cast<unsigned short*>(qbf + 512 * row + ((n * 2) ^ ((row & 7) << 4)))
                    = (unsigned short)f2bf_bits(qacc[ntl][i] + bias);
            }
        }
    }

    // ---- pre-issue ring: rows 0,1 of BOTH tokens; drain under the qr GEMM ----
    const float* srcA = (lane < 32) ? rec : edge;
    const int dloc = (lane * 8) & 255;
    const float* bp0 = srcA + (long)(tok0 + wave * 2) * NREC * EMB + dloc;
    const float* bp1 = bp0 + (long)NREC * EMB;   // token +1
    float4 S00l = *reinterpret_cast<const float4*>(bp0 + 0 * EMB);
    float4 S00h = *reinterpret_cast<const float4*>(bp0 + 0 * EMB + 4);
    float4 S01l = *reinterpret_cast<const float4*>(bp0 + 1 * EMB);
    float4 S01h = *reinterpret_cast<const float4*>(bp0 + 1 * EMB + 4);
    float4 S10l = *reinterpret_cast<const float4*>(bp1 + 0 * EMB);
    float4 S10h = *reinterpret_cast<const float4*>(bp1 + 0 * EMB + 4);
    float4 S11l = *reinterpret_cast<const float4*>(bp1 + 1 * EMB);
    float4 S11h = *reinterpret_cast<const float4*>(bp1 + 1 * EMB + 4);
    __syncthreads();                            // B2: qbf ready

    // ---- 1b: qr = q @ Wr  (M=16,K=256,N=512; 4 n-tiles/wave), stored bf16 ----
    {
        f32x4 racc[4] = {};
        #pragma unroll
        for (int kt = 0; kt < 8; ++kt) {
            int kk = kt * 32 + ((lane >> 4) << 3);
            int row = lane & 15;
            bf16x8 a = *reinterpret_cast<const bf16x8*>(qbf + 512 * row + ((kk * 2) ^ ((row & 7) << 4)));
            #pragma unroll
            for (int ntl = 0; ntl < 4; ++ntl) {
                int nt = wave * 4 + ntl;
                bf16x8 b = load_b_tr<USE_FRAG>(wr_frag + ((nt * 8 + kt) * 64 + lane) * 8,
                                               Wr_w, nt * 16 + (lane & 15), kk, TWO_EMB);
                racc[ntl] = __builtin_amdgcn_mfma_f32_16x16x32_bf16(a, b, racc[ntl], 0, 0, 0);
            }
        }
        #pragma unroll
        for (int ntl = 0; ntl < 4; ++ntl) {
            int n = (wave * 4 + ntl) * 16 + (lane & 15);
            #pragma unroll
            for (int i = 0; i < 4; ++i) {
                int row = ((lane >> 4) << 2) + i;
                *reinterpret_cast<unsigned short*>(qrb + row * 1024 + n * 2)
                    = (unsigned short)f2bf_bits(racc[ntl][i]);
            }
        }
    }
    __syncthreads();                            // B3: qrb ready

    // ---- streaming: both tokens interleaved, ring-2 per token ----
    {
        const int t0 = wave * 2, t1 = t0 + 1;
        uint4 qw0 = *reinterpret_cast<const uint4*>(qrb + t0 * 1024 + lane * 16);
        uint4 qw1 = *reinterpret_cast<const uint4*>(qrb + t1 * 1024 + lane * 16);
        const float Cc = 0.0625f * 1.4426950408889634f;   // 1/sqrt(256)*log2(e)
        float s0 = 0.f, s1 = 0.f;
        float4 x00 = make_float4(0.f, 0.f, 0.f, 0.f), x01 = x00, x10 = x00, x11 = x00;

        #define LDs(base, r, sl, sh) { \
            sl = *reinterpret_cast<const float4*>((base) + (r) * EMB); \
            sh = *reinterpret_cast<const float4*>((base) + (r) * EMB + 4); }
        #define PROCT(qw, sl, sh, ss, z0, z1) { \
            float p = vlo(qw.x)*(sl).x + vhi(qw.x)*(sl).y + vlo(qw.y)*(sl).z + vhi(qw.y)*(sl).w \
                    + vlo(qw.z)*(sh).x + vhi(qw.z)*(sh).y + vlo(qw.w)*(sh).z + vhi(qw.w)*(sh).w; \
            p = wave_sum(p); \
            float e = exp2f(p * Cc);                     /* no-max: |logit| <~ 2 */ \
            ss += e; \
            z0.x += e*(sl).x; z0.y += e*(sl).y; z0.z += e*(sl).z; z0.w += e*(sl).w; \
            z1.x += e*(sh).x; z1.y += e*(sh).y; z1.z += e*(sh).z; z1.w += e*(sh).w; }

        PROCT(qw0, S00l, S00h, s0, x00, x01); LDs(bp0, 2, S00l, S00h);
        PROCT(qw1, S10l, S10h, s1, x10, x11); LDs(bp1, 2, S10l, S10h);
        PROCT(qw0, S01l, S01h, s0, x00, x01); LDs(bp0, 3, S01l, S01h);
        PROCT(qw1, S11l, S11h, s1, x10, x11); LDs(bp1, 3, S11l, S11h);
        PROCT(qw0, S00l, S00h, s0, x00, x01); LDs(bp0, 4, S00l, S00h);
        PROCT(qw1, S10l, S10h, s1, x10, x11); LDs(bp1, 4, S10l, S10h);
        PROCT(qw0, S01l, S01h, s0, x00, x01); LDs(bp0, 5, S01l, S01h);
        PROCT(qw1, S11l, S11h, s1, x10, x11); LDs(bp1, 5, S11l, S11h);
        PROCT(qw0, S00l, S00h, s0, x00, x01); LDs(bp0, 6, S00l, S00h);
        PROCT(qw1, S10l, S10h, s1, x10, x11); LDs(bp1, 6, S10l, S10h);
        PROCT(qw0, S01l, S01h, s0, x00, x01); LDs(bp0, 7, S01l, S01h);
        PROCT(qw1, S11l, S11h, s1, x10, x11); LDs(bp1, 7, S11l, S11h);
        PROCT(qw0, S00l, S00h, s0, x00, x01); LDs(bp0, 8, S00l, S00h);
        PROCT(qw1, S10l, S10h, s1, x10, x11); LDs(bp1, 8, S10l, S10h);
        PROCT(qw0, S01l, S01h, s0, x00, x01); LDs(bp0, 9, S01l, S01h);
        PROCT(qw1, S11l, S11h, s1, x10, x11); LDs(bp1, 9, S11l, S11h);
        PROCT(qw0, S00l, S00h, s0, x00, x01);
        PROCT(qw1, S10l, S10h, s1, x10, x11);
        PROCT(qw0, S01l, S01h, s0, x00, x01);
        PROCT(qw1, S11l, S11h, s1, x10, x11);
        #undef LDs
        #undef PROCT

        const float inv0 = 1.f / s0;
        uint4 w0 = { pack2(x00.x * inv0, x00.y * inv0), pack2(x00.z * inv0, x00.w * inv0),
                     pack2(x01.x * inv0, x01.y * inv0), pack2(x01.z * inv0, x01.w * inv0) };
        *reinterpret_cast<uint4*>(xz + 1024 * t0 + ((lane * 16) ^ ((t0 & 7) << 4))) = w0;
        const float inv1 = 1.f / s1;
        uint4 w1 = { pack2(x10.x * inv1, x10.y * inv1), pack2(x10.z * inv1, x10.w * inv1),
                     pack2(x11.x * inv1, x11.y * inv1), pack2(x11.z * inv1, x11.w * inv1) };
        *reinterpret_cast<uint4*>(xz + 1024 * t1 + ((lane * 16) ^ ((t1 & 7) << 4))) = w1;
    }
    __syncthreads();                            // B4: xbar tile ready

    // ---- ph3: out = q + Wv @ xbar + bv  (M=16,K=512,N=256; 2 n-tiles/wave) ----
    {
        f32x4 oacc[2] = {};
        #pragma unroll
        for (int kt = 0; kt < 16; ++kt) {
            int kk = kt * 32 + ((lane >> 4) << 3);
            int row = lane & 15;
            bf16x8 a = *reinterpret_cast<const bf16x8*>(xz + 1024 * row + ((kk * 2) ^ ((row & 7) << 4)));
            #pragma unroll
            for (int ntl = 0; ntl < 2; ++ntl) {
                int nt = wave * 2 + ntl;
                bf16x8 b = load_b_rm<USE_FRAG>(wv_frag + ((nt * 16 + kt) * 64 + lane) * 8,
                                               Wv_w, nt * 16 + (lane & 15), kk, TWO_EMB);
                oacc[ntl] = __builtin_amdgcn_mfma_f32_16x16x32_bf16(a, b, oacc[ntl], 0, 0, 0);
            }
        }
        #pragma unroll
        for (int ntl = 0; ntl < 2; ++ntl) {
            int n = (wave * 2 + ntl) * 16 + (lane & 15);
            float bv = Wv_b[n];
            #pragma unroll
            for (int i = 0; i < 4; ++i) {
                int row = ((lane >> 4) << 2) + i;
                unsigned short qu = *reinterpret_cast<const unsigned short*>(
                    qbf + 512 * row + ((n * 2) ^ ((row & 7) << 4)));
                float qv = __builtin_bit_cast(float, (unsigned int)qu << 16);
                out[(long)(tok0 + row) * OUTD + n] = qv + oacc[ntl][i] + bv;
            }
        }
    }
}

extern "C" void kernel_launch(void* const* d_in, const int* in_sizes, int n_in,
                              void* d_out, int out_size, void* d_ws, size_t ws_size,
                              hipStream_t stream) {
    const float* rec  = (const float*)d_in[0];
    const float* pep  = (const float*)d_in[1];
    const float* edge = (const float*)d_in[2];
    const float* Wp_w = (const float*)d_in[3];
    const float* Wp_b = (const float*)d_in[4];
    const float* Wr_w = (const float*)d_in[5];
    // d_in[6] = Wr_b : irrelevant (softmax shift invariance)
    const float* Wv_w = (const float*)d_in[7];
    const float* Wv_b = (const float*)d_in[8];
    float* out = (float*)d_out;

    const size_t wp_elems = 16 * 8 * 64 * 8;    // 65536
    const size_t wr_elems = 32 * 8 * 64 * 8;    // 131072
    const size_t wv_elems = 16 * 16 * 64 * 8;   // 131072
    const size_t need = (wp_elems + wr_elems + wv_elems) * sizeof(short);
    short* wp_frag = (short*)d_ws;
    short* wr_frag = wp_frag + wp_elems;
    short* wv_frag = wr_frag + wr_elems;

    if (ws_size >= need) {
        prep_wfrag<<<512, 256, 0, stream>>>(Wp_w, Wr_w, Wv_w, wp_frag, wr_frag, wv_frag);
        ga8_fused<1><<<N_TOK / T_BLK, THREADS, 0, stream>>>(rec, pep, edge, Wp_w, Wp_b, Wr_w,
                                                            Wv_w, Wv_b, wp_frag, wr_frag, wv_frag, out);
    } else {
        ga8_fused<0><<<N_TOK / T_BLK, THREADS, 0, stream>>>(rec, pep, edge, Wp_w, Wp_b, Wr_w,
                                                            Wv_w, Wv_b, wp_frag, wr_frag, wv_frag, out);
    }
}

// Round 11
// 95.703 us; speedup vs baseline: 1.5881x; 1.5734x over previous
//
#include <hip/hip_runtime.h>
#include <hip/hip_bf16.h>

#define N_TOK   16384   // B * N_PEP
#define NREC    10
#define EMB     256
#define TWO_EMB 512
#define OUTD    256
#define T_BLK   16      // tokens per block
#define THREADS 512     // 8 waves; wave w owns tokens 2w, 2w+1 in streaming phase

typedef __bf16 bf16x8 __attribute__((ext_vector_type(8)));
typedef float  f32x4  __attribute__((ext_vector_type(4)));

static __device__ __forceinline__ unsigned int f2bf_bits(float f) {
    unsigned int u = __builtin_bit_cast(unsigned int, f);
    u = (u + 0x7fffu + ((u >> 16) & 1u)) >> 16;   // RNE bf16
    return u & 0xffffu;
}
static __device__ __forceinline__ unsigned int pack2(float a, float b) {
    return f2bf_bits(a) | (f2bf_bits(b) << 16);
}
static __device__ __forceinline__ float bflo(unsigned int u) {
    return __builtin_bit_cast(float, u << 16);
}
static __device__ __forceinline__ float bfhi(unsigned int u) {
    return __builtin_bit_cast(float, u & 0xffff0000u);
}

// 64-lane sum: 4 DPP row_ror adds (16-lane ring reduce at VALU latency) then
// two cross-group shuffles. Chain = 4 VALU + 2 DS (was 6 dependent DS ops).
// Validated spill-free at VGPR=64 in R8.
static __device__ __forceinline__ float wave_sum(float p) {
    p += __builtin_bit_cast(float, __builtin_amdgcn_update_dpp(
             0, __builtin_bit_cast(int, p), 0x121, 0xf, 0xf, true));   // ror1
    p += __builtin_bit_cast(float, __builtin_amdgcn_update_dpp(
             0, __builtin_bit_cast(int, p), 0x122, 0xf, 0xf, true));   // ror2
    p += __builtin_bit_cast(float, __builtin_amdgcn_update_dpp(
             0, __builtin_bit_cast(int, p), 0x124, 0xf, 0xf, true));   // ror4
    p += __builtin_bit_cast(float, __builtin_amdgcn_update_dpp(
             0, __builtin_bit_cast(int, p), 0x128, 0xf, 0xf, true));   // ror8
    p += __shfl_xor(p, 16);
    p += __shfl_xor(p, 32);
    return p;
}

// ---------------- weight fragment prep (bf16, MFMA B-fragment order) ----------
// wp_frag: [16 nt][8 kt][64][8]   q GEMM    B[n=o][k=d] = Wp[n*256+k]
// wr_frag: [32 nt][8 kt][64][8]   qr GEMM   B[n=d][k=o] = Wr[k*512+n]  (transposed use)
// wv_frag: [16 nt][16 kt][64][8]  out GEMM  B[n=o][k=d] = Wv[n*512+k]
__global__ void prep_wfrag(const float* __restrict__ Wp,
                           const float* __restrict__ Wr,
                           const float* __restrict__ Wv,
                           short* __restrict__ wp_frag,
                           short* __restrict__ wr_frag,
                           short* __restrict__ wv_frag) {
    int idx = blockIdx.x * blockDim.x + threadIdx.x;   // grid covers 131072
    if (idx < 16 * 8 * 64 * 8) {
        int j = idx & 7, lane = (idx >> 3) & 63, kt = (idx >> 9) & 7, nt = idx >> 12;
        int n = nt * 16 + (lane & 15), k = kt * 32 + ((lane >> 4) << 3) + j;
        wp_frag[idx] = (short)f2bf_bits(Wp[n * EMB + k]);
    }
    if (idx < 32 * 8 * 64 * 8) {
        int j = idx & 7, lane = (idx >> 3) & 63, kt = (idx >> 9) & 7, nt = idx >> 12;
        int n = nt * 16 + (lane & 15), k = kt * 32 + ((lane >> 4) << 3) + j;
        wr_frag[idx] = (short)f2bf_bits(Wr[k * TWO_EMB + n]);
    }
    if (idx < 16 * 16 * 64 * 8) {
        int j = idx & 7, lane = (idx >> 3) & 63, kt = (idx >> 9) & 15, nt = idx >> 13;
        int n = nt * 16 + (lane & 15), k = kt * 32 + ((lane >> 4) << 3) + j;
        wv_frag[idx] = (short)f2bf_bits(Wv[n * TWO_EMB + k]);
    }
}

// B-fragment loaders (frag path or direct-from-f32 fallback)
template<int USE_FRAG>
static __device__ __forceinline__ bf16x8 load_b_rm(const short* __restrict__ frag,
                                                   const float* __restrict__ W,
                                                   int n, int k, int ld) {
    if constexpr (USE_FRAG) {
        return *reinterpret_cast<const bf16x8*>(frag);
    } else {
        const float* s = W + (long)n * ld + k;
        float4 f0 = *reinterpret_cast<const float4*>(s);
        float4 f1 = *reinterpret_cast<const float4*>(s + 4);
        uint4 t = { pack2(f0.x, f0.y), pack2(f0.z, f0.w), pack2(f1.x, f1.y), pack2(f1.z, f1.w) };
        return __builtin_bit_cast(bf16x8, t);
    }
}
template<int USE_FRAG>
static __device__ __forceinline__ bf16x8 load_b_tr(const short* __restrict__ frag,
                                                   const float* __restrict__ W,
                                                   int n, int k, int ld) {
    if constexpr (USE_FRAG) {
        return *reinterpret_cast<const bf16x8*>(frag);
    } else {
        unsigned int p[4];
        #pragma unroll
        for (int jj = 0; jj < 4; ++jj)
            p[jj] = pack2(W[(long)(k + 2 * jj) * ld + n], W[(long)(k + 2 * jj + 1) * ld + n]);
        uint4 t = { p[0], p[1], p[2], p[3] };
        return __builtin_bit_cast(bf16x8, t);
    }
}

// ---- one-pass streaming for a token: xbar = (sum e_r x_r) / (sum e_r) --------
// Normalization commutes with the value sum: each row loaded ONCE, dotted,
// reduced (DPP), weighted, accumulated, discarded. Peak live ~52 VGPRs.
static __device__ __forceinline__ void stream_token(
    const float* __restrict__ bp,            // this lane's base (token,row0,dloc)
    const unsigned char* __restrict__ qrb,
    unsigned char* __restrict__ xz,
    int t, int lane,
    float4 s0l, float4 s0h, float4 s1l, float4 s1h,
    float4 s2l, float4 s2h, float4 s3l, float4 s3h)   // rows 0..3 in flight
{
    uint4 qw = *reinterpret_cast<const uint4*>(qrb + t * 1024 + lane * 16);
    const float qa0 = bflo(qw.x), qa1 = bfhi(qw.x), qa2 = bflo(qw.y), qa3 = bfhi(qw.y);
    const float qa4 = bflo(qw.z), qa5 = bfhi(qw.z), qa6 = bflo(qw.w), qa7 = bfhi(qw.w);
    const float C = 0.0625f * 1.4426950408889634f;   // 1/sqrt(256) * log2(e)

    float s = 0.f;
    float4 xb0 = make_float4(0.f, 0.f, 0.f, 0.f), xb1 = xb0;

    #define LD(r, sl, sh) { sl = *reinterpret_cast<const float4*>(bp + (r) * EMB); \
                            sh = *reinterpret_cast<const float4*>(bp + (r) * EMB + 4); }
    #define PROC(sl, sh) { \
        float p = qa0*(sl).x + qa1*(sl).y + qa2*(sl).z + qa3*(sl).w \
                + qa4*(sh).x + qa5*(sh).y + qa6*(sh).z + qa7*(sh).w; \
        p = wave_sum(p); \
        float e = exp2f(p * C);                      /* no-max: |logit| <~ 2 */ \
        s += e; \
        xb0.x += e*(sl).x; xb0.y += e*(sl).y; xb0.z += e*(sl).z; xb0.w += e*(sl).w; \
        xb1.x += e*(sh).x; xb1.y += e*(sh).y; xb1.z += e*(sh).z; xb1.w += e*(sh).w; }

    PROC(s0l, s0h); LD(4, s0l, s0h);
    PROC(s1l, s1h); LD(5, s1l, s1h);
    PROC(s2l, s2h); LD(6, s2l, s2h);
    PROC(s3l, s3h); LD(7, s3l, s3h);
    PROC(s0l, s0h); LD(8, s0l, s0h);
    PROC(s1l, s1h); LD(9, s1l, s1h);
    PROC(s2l, s2h);
    PROC(s3l, s3h);
    PROC(s0l, s0h);
    PROC(s1l, s1h);
    #undef LD
    #undef PROC

    const float inv = 1.f / s;
    uint4 wv4 = { pack2(xb0.x * inv, xb0.y * inv), pack2(xb0.z * inv, xb0.w * inv),
                  pack2(xb1.x * inv, xb1.y * inv), pack2(xb1.z * inv, xb1.w * inv) };
    *reinterpret_cast<uint4*>(xz + 1024 * t + ((lane * 16) ^ ((t & 7) << 4))) = wv4;
}

// ---------------- fused kernel (commuted-projection formulation) --------------
// per token t:  q  = Wp@pep + bp                      (MFMA; kept in qbf as bf16)
//               qr = Wr^T q                           (MFMA; Wr_b drops: softmax shift-inv)
//               e_r = exp((qr . x_r)/16)              (streamed f32, one pass)
//               xbar = (sum e_r x_r) / (sum e_r)
//               out = q + Wv@xbar + bv                (MFMA; sum(attn)=1 folds bias)
template<int USE_FRAG>
__launch_bounds__(THREADS, 4)
__global__ void ga9_fused(const float* __restrict__ rec,
                          const float* __restrict__ pep,
                          const float* __restrict__ edge,
                          const float* __restrict__ Wp_w,
                          const float* __restrict__ Wp_b,
                          const float* __restrict__ Wr_w,
                          const float* __restrict__ Wv_w,
                          const float* __restrict__ Wv_b,
                          const short* __restrict__ wp_frag,
                          const short* __restrict__ wr_frag,
                          const short* __restrict__ wv_frag,
                          float* __restrict__ out) {
    // xz: pep bf16 A-tile (512B rows) in 1a, then xbar bf16 A-tile (1024B rows) in ph3
    __shared__ __align__(16) unsigned char xz[T_BLK * 1024];       // 16 KB
    __shared__ __align__(16) unsigned char qbf[T_BLK * 512];       // 8 KB (q bf16 A-tile)
    __shared__ __align__(16) unsigned char qrb[T_BLK * 1024];      // 16 KB (qr bf16 [t][512])

    const int tid  = threadIdx.x;
    const int lane = tid & 63;
    const int wave = tid >> 6;
    const int tok0 = blockIdx.x * T_BLK;

    // ---- stage pep tile as bf16 (swizzled) ----
    #pragma unroll
    for (int it = 0; it < 2; ++it) {
        int idx = tid + it * THREADS;          // 16 rows x 64 float4
        int row = idx >> 6, d4 = (idx & 63) << 2;
        float4 f = *reinterpret_cast<const float4*>(pep + (long)(tok0 + row) * EMB + d4);
        uint2 w = { pack2(f.x, f.y), pack2(f.z, f.w) };
        *reinterpret_cast<uint2*>(xz + 512 * row + ((d4 * 2) ^ ((row & 7) << 4))) = w;
    }
    __syncthreads();                            // B1: pep tile ready

    // ---- 1a: q = pep @ Wp^T + bp  (M=16,K=256,N=256; 2 n-tiles/wave) ----
    {
        f32x4 qacc[2] = {};
        #pragma unroll
        for (int kt = 0; kt < 8; ++kt) {
            int kk = kt * 32 + ((lane >> 4) << 3);
            int row = lane & 15;
            bf16x8 a = *reinterpret_cast<const bf16x8*>(xz + 512 * row + ((kk * 2) ^ ((row & 7) << 4)));
            #pragma unroll
            for (int ntl = 0; ntl < 2; ++ntl) {
                int nt = wave * 2 + ntl;
                bf16x8 b = load_b_rm<USE_FRAG>(wp_frag + ((nt * 8 + kt) * 64 + lane) * 8,
                                               Wp_w, nt * 16 + (lane & 15), kk, EMB);
                qacc[ntl] = __builtin_amdgcn_mfma_f32_16x16x32_bf16(a, b, qacc[ntl], 0, 0, 0);
            }
        }
        #pragma unroll
        for (int ntl = 0; ntl < 2; ++ntl) {
            int n = (wave * 2 + ntl) * 16 + (lane & 15);
            float bias = Wp_b[n];
            #pragma unroll
            for (int i = 0; i < 4; ++i) {
                int row = ((lane >> 4) << 2) + i;
                float v = qacc[ntl][i] + bias;
                *reinterpret_cast<unsigned short*>(qbf + 512 * row + ((n * 2) ^ ((row & 7) << 4)))
                    = (unsigned short)f2bf_bits(v);
            }
        }
    }

    // ---- issue token-A rows 0..3; they drain under the qr GEMM ----
    const float* srcA = (lane < 32) ? rec : edge;
    const int dloc = (lane * 8) & 255;
    const float* baseA = srcA + (long)(tok0 + wave * 2) * NREC * EMB + dloc;
    const float* baseB = baseA + (long)NREC * EMB;   // token A+1
    float4 a0l = *reinterpret_cast<const float4*>(baseA + 0 * EMB);
    float4 a0h = *reinterpret_cast<const float4*>(baseA + 0 * EMB + 4);
    float4 a1l = *reinterpret_cast<const float4*>(baseA + 1 * EMB);
    float4 a1h = *reinterpret_cast<const float4*>(baseA + 1 * EMB + 4);
    float4 a2l = *reinterpret_cast<const float4*>(baseA + 2 * EMB);
    float4 a2h = *reinterpret_cast<const float4*>(baseA + 2 * EMB + 4);
    float4 a3l = *reinterpret_cast<const float4*>(baseA + 3 * EMB);
    float4 a3h = *reinterpret_cast<const float4*>(baseA + 3 * EMB + 4);
    __syncthreads();                            // B2: qbf ready

    // ---- 1b: qr = q @ Wr  (M=16,K=256,N=512; 4 n-tiles/wave), stored bf16 ----
    {
        f32x4 racc[4] = {};
        #pragma unroll
        for (int kt = 0; kt < 8; ++kt) {
            int kk = kt * 32 + ((lane >> 4) << 3);
            int row = lane & 15;
            bf16x8 a = *reinterpret_cast<const bf16x8*>(qbf + 512 * row + ((kk * 2) ^ ((row & 7) << 4)));
            #pragma unroll
            for (int ntl = 0; ntl < 4; ++ntl) {
                int nt = wave * 4 + ntl;
                bf16x8 b = load_b_tr<USE_FRAG>(wr_frag + ((nt * 8 + kt) * 64 + lane) * 8,
                                               Wr_w, nt * 16 + (lane & 15), kk, TWO_EMB);
                racc[ntl] = __builtin_amdgcn_mfma_f32_16x16x32_bf16(a, b, racc[ntl], 0, 0, 0);
            }
        }
        #pragma unroll
        for (int ntl = 0; ntl < 4; ++ntl) {
            int n = (wave * 4 + ntl) * 16 + (lane & 15);
            #pragma unroll
            for (int i = 0; i < 4; ++i) {
                int row = ((lane >> 4) << 2) + i;
                *reinterpret_cast<unsigned short*>(qrb + row * 1024 + n * 2)
                    = (unsigned short)f2bf_bits(racc[ntl][i]);
            }
        }
    }
    __syncthreads();                            // B3: qrb ready

    // ---- streaming: token A (ring pre-issued), then token B ----
    stream_token(baseA, qrb, xz, wave * 2, lane, a0l, a0h, a1l, a1h, a2l, a2h, a3l, a3h);
    {
        float4 b0l = *reinterpret_cast<const float4*>(baseB + 0 * EMB);
        float4 b0h = *reinterpret_cast<const float4*>(baseB + 0 * EMB + 4);
        float4 b1l = *reinterpret_cast<const float4*>(baseB + 1 * EMB);
        float4 b1h = *reinterpret_cast<const float4*>(baseB + 1 * EMB + 4);
        float4 b2l = *reinterpret_cast<const float4*>(baseB + 2 * EMB);
        float4 b2h = *reinterpret_cast<const float4*>(baseB + 2 * EMB + 4);
        float4 b3l = *reinterpret_cast<const float4*>(baseB + 3 * EMB);
        float4 b3h = *reinterpret_cast<const float4*>(baseB + 3 * EMB + 4);
        stream_token(baseB, qrb, xz, wave * 2 + 1, lane, b0l, b0h, b1l, b1h, b2l, b2h, b3l, b3h);
    }
    __syncthreads();                            // B4: xbar tile ready

    // ---- ph3: out = q + Wv @ xbar + bv  (M=16,K=512,N=256; 2 n-tiles/wave) ----
    {
        f32x4 oacc[2] = {};
        #pragma unroll
        for (int kt = 0; kt < 16; ++kt) {
            int kk = kt * 32 + ((lane >> 4) << 3);
            int row = lane & 15;
            bf16x8 a = *reinterpret_cast<const bf16x8*>(xz + 1024 * row + ((kk * 2) ^ ((row & 7) << 4)));
            #pragma unroll
            for (int ntl = 0; ntl < 2; ++ntl) {
                int nt = wave * 2 + ntl;
                bf16x8 b = load_b_rm<USE_FRAG>(wv_frag + ((nt * 16 + kt) * 64 + lane) * 8,
                                               Wv_w, nt * 16 + (lane & 15), kk, TWO_EMB);
                oacc[ntl] = __builtin_amdgcn_mfma_f32_16x16x32_bf16(a, b, oacc[ntl], 0, 0, 0);
            }
        }
        #pragma unroll
        for (int ntl = 0; ntl < 2; ++ntl) {
            int n = (wave * 2 + ntl) * 16 + (lane & 15);
            float bv = Wv_b[n];
            #pragma unroll
            for (int i = 0; i < 4; ++i) {
                int row = ((lane >> 4) << 2) + i;
                unsigned short qu = *reinterpret_cast<const unsigned short*>(
                    qbf + 512 * row + ((n * 2) ^ ((row & 7) << 4)));
                float qv = __builtin_bit_cast(float, (unsigned int)qu << 16);
                out[(long)(tok0 + row) * OUTD + n] = qv + oacc[ntl][i] + bv;
            }
        }
    }
}

extern "C" void kernel_launch(void* const* d_in, const int* in_sizes, int n_in,
                              void* d_out, int out_size, void* d_ws, size_t ws_size,
                              hipStream_t stream) {
    const float* rec  = (const float*)d_in[0];
    const float* pep  = (const float*)d_in[1];
    const float* edge = (const float*)d_in[2];
    const float* Wp_w = (const float*)d_in[3];
    const float* Wp_b = (const float*)d_in[4];
    const float* Wr_w = (const float*)d_in[5];
    // d_in[6] = Wr_b : irrelevant (softmax shift invariance)
    const float* Wv_w = (const float*)d_in[7];
    const float* Wv_b = (const float*)d_in[8];
    float* out = (float*)d_out;

    const size_t wp_elems = 16 * 8 * 64 * 8;    // 65536
    const size_t wr_elems = 32 * 8 * 64 * 8;    // 131072
    const size_t wv_elems = 16 * 16 * 64 * 8;   // 131072
    const size_t need = (wp_elems + wr_elems + wv_elems) * sizeof(short);
    short* wp_frag = (short*)d_ws;
    short* wr_frag = wp_frag + wp_elems;
    short* wv_frag = wr_frag + wr_elems;

    if (ws_size >= need) {
        prep_wfrag<<<512, 256, 0, stream>>>(Wp_w, Wr_w, Wv_w, wp_frag, wr_frag, wv_frag);
        ga9_fused<1><<<N_TOK / T_BLK, THREADS, 0, stream>>>(rec, pep, edge, Wp_w, Wp_b, Wr_w,
                                                            Wv_w, Wv_b, wp_frag, wr_frag, wv_frag, out);
    } else {
        ga9_fused<0><<<N_TOK / T_BLK, THREADS, 0, stream>>>(rec, pep, edge, Wp_w, Wp_b, Wr_w,
                                                            Wv_w, Wv_b, wp_frag, wr_frag, wv_frag, out);
    }
}